// Round 5
// baseline (97.174 us; speedup 1.0000x reference)
//
#include <hip/hip_runtime.h>
#include <hip/hip_bf16.h>

typedef __bf16 bf16x8 __attribute__((ext_vector_type(8)));
typedef float f32x4 __attribute__((ext_vector_type(4)));
typedef float f32x16 __attribute__((ext_vector_type(16)));

#define MFMA16(a, b, c) __builtin_amdgcn_mfma_f32_16x16x32_bf16(a, b, c, 0, 0, 0)
#define MFMA32(a, b, c) __builtin_amdgcn_mfma_f32_32x32x16_bf16(a, b, c, 0, 0, 0)

static constexpr int NSP = 4096;   // H*W
static constexpr float SCALE_L2E = 0.25f * 1.4426950408889634f;  // SCALE * log2(e)

__device__ __forceinline__ bf16x8 ld_frag(const void* p) {
  int4 v = *(const int4*)p;
  return __builtin_bit_cast(bf16x8, v);
}

__device__ __forceinline__ unsigned pk2(float a, float b) {
  unsigned short x = __builtin_bit_cast(unsigned short, (__bf16)a);
  unsigned short y = __builtin_bit_cast(unsigned short, (__bf16)b);
  return (unsigned)x | ((unsigned)y << 16);
}

__device__ __forceinline__ void load_lds16(const void* g, void* l) {
  __builtin_amdgcn_global_load_lds(
      (const __attribute__((address_space(1))) unsigned*)g,
      (__attribute__((address_space(3))) unsigned*)l, 16, 0, 0);
}

// ---------------- K0: weight prep (fp32 -> bf16, fold SCALE*log2e into Wq/bq)
__global__ void k_prep(const float* __restrict__ Wq, const float* __restrict__ bq,
                       const float* __restrict__ Wk, const float* __restrict__ Wv,
                       const float* __restrict__ Wo,
                       __bf16* __restrict__ wqb, __bf16* __restrict__ wkb,
                       __bf16* __restrict__ wvb, __bf16* __restrict__ wob,
                       float* __restrict__ bqs) {
  int i = blockIdx.x * 256 + threadIdx.x;
  if (i < 16384)      wqb[i]          = (__bf16)(Wq[i] * SCALE_L2E);
  else if (i < 49152) wkb[i - 16384]  = (__bf16)Wk[i - 16384];
  else if (i < 81920) wvb[i - 49152]  = (__bf16)Wv[i - 49152];
  else if (i < 98304) wob[i - 81920]  = (__bf16)Wo[i - 81920];
  if (i < 128) bqs[i] = bq[i] * SCALE_L2E;
}

// Per-wave: write D[o][n] fragments transposed into a [16 n][128 o] bf16 LDS
// tile (XOR swizzled), then copy rows coalesced to dst.
template <bool SWZ>
__device__ __forceinline__ void store_tile_T(char* myt, const f32x4* acc, int g, int r,
                                             __bf16* dst_base) {
#pragma unroll
  for (int oc = 0; oc < 8; ++oc) {
#pragma unroll
    for (int rr = 0; rr < 4; ++rr) {
      int o = oc * 16 + g * 4 + rr;
      int byte = (r << 8) + (o << 1);
      byte ^= (r & 7) << 4;
      *(__bf16*)(myt + byte) = (__bf16)acc[oc][rr];
    }
  }
  int l = g * 16 + r;
#pragma unroll
  for (int p = 0; p < 4; ++p) {
    int u = p * 64 + l, row = u >> 4, seg = u & 15;
    int byte = (row << 8) + (seg << 4);
    if (!SWZ) byte ^= (row & 7) << 4;
    int4 v = *(int4*)(myt + byte);
    *(int4*)(dst_base + row * 128 + seg * 8) = v;
  }
}

// ---------------- K1: fused Q / K+V projections ----------------------------
// grid 512: bid<256 -> Q-part, else KV-part.
__global__ __launch_bounds__(256) void k_proj(const float* __restrict__ xq,
                                              const float* __restrict__ xkv,
                                              const __bf16* __restrict__ wqb,
                                              const __bf16* __restrict__ wkb,
                                              const __bf16* __restrict__ wvb,
                                              const float* __restrict__ bqs,
                                              const float* __restrict__ bk,
                                              const float* __restrict__ bv,
                                              __bf16* __restrict__ Qt,
                                              __bf16* __restrict__ Kt,
                                              __bf16* __restrict__ Vm) {
  const int t = threadIdx.x, w = t >> 6, l = t & 63, r = l & 15, g = l >> 4;
  __shared__ __align__(16) char lds[16384];
  char* myt = lds + (w << 12);

  if (blockIdx.x < 256) {
    const int b = blockIdx.x >> 6;
    const int n0 = (blockIdx.x & 63) << 6;
    const int nl = n0 + (w << 4) + r;
    const float* xb = xq + ((size_t)b << 19);
    bf16x8 bx[4];
#pragma unroll
    for (int cc = 0; cc < 4; ++cc) {
#pragma unroll
      for (int i = 0; i < 8; ++i) {
        int c = cc * 32 + g * 8 + i;
        bx[cc][i] = (__bf16)xb[c * 4096 + nl];
      }
    }
    f32x4 acc[8];
#pragma unroll
    for (int oc = 0; oc < 8; ++oc)
#pragma unroll
      for (int rr = 0; rr < 4; ++rr) acc[oc][rr] = bqs[oc * 16 + g * 4 + rr];
#pragma unroll
    for (int oc = 0; oc < 8; ++oc) {
#pragma unroll
      for (int cc = 0; cc < 4; ++cc) {
        bf16x8 a = ld_frag(wqb + (oc * 16 + r) * 128 + cc * 32 + g * 8);
        acc[oc] = MFMA16(a, bx[cc], acc[oc]);
      }
    }
    store_tile_T<false>(myt, acc, g, r, Qt + ((size_t)(b * NSP + n0 + w * 16)) * 128);
  } else {
    const int bid = blockIdx.x - 256;
    const int b = bid >> 6;
    const int n0 = (bid & 63) << 6;
    const int nl = n0 + (w << 4) + r;
    const float* xb = xkv + ((size_t)b << 20);
    bf16x8 bx[8];
#pragma unroll
    for (int cc = 0; cc < 8; ++cc) {
#pragma unroll
      for (int i = 0; i < 8; ++i) {
        int c = cc * 32 + g * 8 + i;
        bx[cc][i] = (__bf16)xb[(size_t)c * 4096 + nl];
      }
    }
    f32x4 acc[8];
#pragma unroll
    for (int oc = 0; oc < 8; ++oc)
#pragma unroll
      for (int rr = 0; rr < 4; ++rr) acc[oc][rr] = bk[oc * 16 + g * 4 + rr];
#pragma unroll
    for (int oc = 0; oc < 8; ++oc) {
#pragma unroll
      for (int cc = 0; cc < 8; ++cc) {
        bf16x8 a = ld_frag(wkb + (oc * 16 + r) * 256 + cc * 32 + g * 8);
        acc[oc] = MFMA16(a, bx[cc], acc[oc]);
      }
    }
    store_tile_T<true>(myt, acc, g, r, Kt + ((size_t)(b * NSP + n0 + w * 16)) * 128);

    f32x4 av[8];
#pragma unroll
    for (int oc = 0; oc < 8; ++oc)
#pragma unroll
      for (int rr = 0; rr < 4; ++rr) av[oc][rr] = bv[oc * 16 + g * 4 + rr];
#pragma unroll
    for (int oc = 0; oc < 8; ++oc) {
#pragma unroll
      for (int cc = 0; cc < 8; ++cc) {
        bf16x8 a = ld_frag(wvb + (oc * 16 + r) * 256 + cc * 32 + g * 8);
        av[oc] = MFMA16(a, bx[cc], av[oc]);
      }
    }
    // V stored [B][128][N], pre-swizzled: key n at n ^ ((ch&7)<<3)
#pragma unroll
    for (int oc = 0; oc < 8; ++oc) {
#pragma unroll
      for (int rr = 0; rr < 4; ++rr) {
        int o = oc * 16 + g * 4 + rr;
        Vm[((size_t)(b * 128 + o) << 12) + (nl ^ ((o & 7) << 3))] = (__bf16)av[oc][rr];
      }
    }
  }
}

// ---------------- K3: flash attention, 32x32 MFMA, P kept in registers -----
// 4 waves x 32 q-rows = 128 q/block. Swapped QK^T: s = mfma32(K,Q): lane
// (q=l&31, hi=l>>5) holds S[key=crow(reg,hi)][q], crow=(reg&3)+8*(reg>>2)+4hi.
// Lane pair (l, l^32) holds complementary key-halves of the SAME query ->
// softmax reduce = in-lane tree + one shfl_xor(32); P redistributed to PV
// B-fragments via pk2 + shfl_xor(32) (no LDS round-trip).
template <int SPLIT>
__global__ __launch_bounds__(256, 2) void k_flash(const __bf16* __restrict__ Qt,
                                                  const __bf16* __restrict__ Kt,
                                                  const __bf16* __restrict__ Vm,
                                                  __bf16* __restrict__ Op,
                                                  float2* __restrict__ Ml) {
  const int bid = blockIdx.x;
  const int combo = bid & (4 * SPLIT - 1), qtile = bid / (4 * SPLIT);
  const int b = combo & 3, ks = combo >> 2;
  const int q0 = qtile << 7;
  const int NK = NSP / SPLIT;
  const int t = threadIdx.x, w = t >> 6, l = t & 63;
  const int q31 = l & 31, hi = l >> 5;
  const int swz = (q31 & 7) << 4;

  __shared__ __align__(16) char kl[2][16384];
  __shared__ __align__(16) char vl[2][16384];

  // Q fragments: 8 chunks of 16 ch; B-frag: col=q31, k = hi*8+j
  const __bf16* qp = Qt + ((size_t)(b * NSP + q0 + w * 32 + q31)) * 128;
  bf16x8 qf[8];
#pragma unroll
  for (int cc = 0; cc < 8; ++cc) qf[cc] = ld_frag(qp + cc * 16 + hi * 8);

  f32x16 acc[4];
#pragma unroll
  for (int c = 0; c < 4; ++c)
#pragma unroll
    for (int i = 0; i < 16; ++i) acc[c][i] = 0.f;
  float m = -1e30f, lsum = 0.f;

  const char* kbase = (const char*)(Kt + ((size_t)(b * NSP) + ks * NK) * 128);
  const char* vbase = (const char*)(Vm + (size_t)b * 128 * NSP + ks * NK);

  auto STAGE = [&](int bi, int tt) {
#pragma unroll
    for (int i = 0; i < 4; ++i) {  // K: 16 KB (pre-swizzled rows of 256 B)
      int c = i * 4 + w;
      load_lds16(kbase + tt * 16384 + c * 1024 + l * 16, &kl[bi][c * 1024]);
    }
#pragma unroll
    for (int i = 0; i < 4; ++i) {  // V: 128 ch rows x 128 B
      int c0 = (i * 4 + w) * 8;
      int ch = c0 + (l >> 3);
      load_lds16(vbase + (size_t)ch * 8192 + tt * 128 + (l & 7) * 16,
                 &vl[bi][c0 * 128]);
    }
  };

  STAGE(0, 0);
  __syncthreads();

  const int nit = NK / 64;
  for (int it = 0; it < nit; ++it) {
    const int cur = it & 1;
    if (it + 1 < nit) STAGE(cur ^ 1, it + 1);

    // ---- QK^T: s = mfma32(K_frag, Q_frag) ----
    const char* kt = kl[cur];
    f32x16 s0 = {}, s1 = {};
    __builtin_amdgcn_s_setprio(1);
#pragma unroll
    for (int cc = 0; cc < 8; ++cc) {
      int cb = (cc * 32 + hi * 16);
      int a0 = (q31 << 8) + (cb ^ swz);
      s0 = MFMA32(ld_frag(kt + a0), qf[cc], s0);
      int a1 = ((32 + q31) << 8) + (cb ^ swz);
      s1 = MFMA32(ld_frag(kt + a1), qf[cc], s1);
    }
    __builtin_amdgcn_s_setprio(0);

    // ---- per-query online softmax (lane pair shares one query) ----
    float mx = s0[0];
#pragma unroll
    for (int i = 1; i < 16; ++i) mx = fmaxf(mx, s0[i]);
#pragma unroll
    for (int i = 0; i < 16; ++i) mx = fmaxf(mx, s1[i]);
    mx = fmaxf(mx, __shfl_xor(mx, 32));
    if (__any(mx - m > 8.f)) {
      float mn = fmaxf(m, mx);
      float a = exp2f(m - mn);
      m = mn;
      lsum *= a;
#pragma unroll
      for (int c = 0; c < 4; ++c)
#pragma unroll
        for (int i = 0; i < 16; ++i) acc[c][i] *= a;
    }
    float rs = 0.f;
#pragma unroll
    for (int i = 0; i < 16; ++i) {
      s0[i] = exp2f(s0[i] - m);
      rs += s0[i];
    }
#pragma unroll
    for (int i = 0; i < 16; ++i) {
      s1[i] = exp2f(s1[i] - m);
      rs += s1[i];
    }
    rs += __shfl_xor(rs, 32);
    lsum += rs;

    // ---- P -> bf16 in registers + cross-half exchange (no LDS) ----
    unsigned o0[4][2], o1[4][2], r0[4][2], r1[4][2];
#pragma unroll
    for (int q4 = 0; q4 < 4; ++q4) {
      o0[q4][0] = pk2(s0[4 * q4 + 0], s0[4 * q4 + 1]);
      o0[q4][1] = pk2(s0[4 * q4 + 2], s0[4 * q4 + 3]);
      o1[q4][0] = pk2(s1[4 * q4 + 0], s1[4 * q4 + 1]);
      o1[q4][1] = pk2(s1[4 * q4 + 2], s1[4 * q4 + 3]);
    }
#pragma unroll
    for (int q4 = 0; q4 < 4; ++q4) {
      r0[q4][0] = __shfl_xor(o0[q4][0], 32);
      r0[q4][1] = __shfl_xor(o0[q4][1], 32);
      r1[q4][0] = __shfl_xor(o1[q4][0], 32);
      r1[q4][1] = __shfl_xor(o1[q4][1], 32);
    }

    // ---- PV: acc = mfma32(V^T_frag, P_frag) ----
    const char* vt = vl[cur];
    __builtin_amdgcn_s_setprio(1);
#pragma unroll
    for (int kb = 0; kb < 2; ++kb) {
      uint4 f0, f1;
      f0.x = hi ? r0[2 * kb + 1][0] : o0[2 * kb][0];
      f0.y = hi ? r0[2 * kb + 1][1] : o0[2 * kb][1];
      f0.z = hi ? o0[2 * kb + 1][0] : r0[2 * kb][0];
      f0.w = hi ? o0[2 * kb + 1][1] : r0[2 * kb][1];
      f1.x = hi ? r1[2 * kb + 1][0] : o1[2 * kb][0];
      f1.y = hi ? r1[2 * kb + 1][1] : o1[2 * kb][1];
      f1.z = hi ? o1[2 * kb + 1][0] : r1[2 * kb][0];
      f1.w = hi ? o1[2 * kb + 1][1] : r1[2 * kb][1];
      bf16x8 pf0 = __builtin_bit_cast(bf16x8, f0);
      bf16x8 pf1 = __builtin_bit_cast(bf16x8, f1);
#pragma unroll
      for (int cht = 0; cht < 4; ++cht) {
        int rowb = (cht * 32 + q31) << 7;
        int va0 = rowb + ((kb * 32 + hi * 16) ^ swz);
        acc[cht] = MFMA32(ld_frag(vt + va0), pf0, acc[cht]);
        int va1 = rowb + ((64 + kb * 32 + hi * 16) ^ swz);
        acc[cht] = MFMA32(ld_frag(vt + va1), pf1, acc[cht]);
      }
    }
    __builtin_amdgcn_s_setprio(0);
    __syncthreads();
  }

  // ---- partial store: lane holds O^T[ch=cht*32+crow(reg,hi)][q=q31] ----
  float inv = 1.f / lsum;
  const size_t orow = (size_t)((ks * 4 + b) * NSP + q0 + w * 32 + q31) * 128;
#pragma unroll
  for (int cht = 0; cht < 4; ++cht) {
#pragma unroll
    for (int qq = 0; qq < 4; ++qq) {
      uint2 v;
      v.x = pk2(acc[cht][4 * qq + 0] * inv, acc[cht][4 * qq + 1] * inv);
      v.y = pk2(acc[cht][4 * qq + 2] * inv, acc[cht][4 * qq + 3] * inv);
      *(uint2*)(Op + orow + cht * 32 + qq * 8 + hi * 4) = v;
    }
  }
  if (hi == 0) {
    Ml[(size_t)(ks * 4 + b) * NSP + q0 + w * 32 + q31] = make_float2(m, lsum);
  }
}

// ---------------- K4: combine splits + out projection + residual -----------
template <int SPLIT>
__global__ __launch_bounds__(256) void k_oproj(const __bf16* __restrict__ Op,
                                               const float2* __restrict__ Ml,
                                               const __bf16* __restrict__ wob,
                                               const float* __restrict__ bo,
                                               const float* __restrict__ xq,
                                               float* __restrict__ out) {
  const int b = blockIdx.x >> 6;
  const int n0 = (blockIdx.x & 63) << 6;
  const int t = threadIdx.x, w = t >> 6, l = t & 63, r = l & 15, g = l >> 4;
  const int nl = n0 + (w << 4) + r;

  float2 e[SPLIT];
  float M = -1e30f;
#pragma unroll
  for (int s = 0; s < SPLIT; ++s) {
    e[s] = Ml[(size_t)(s * 4 + b) * NSP + nl];
    M = fmaxf(M, e[s].x);
  }
  float wk[SPLIT], den = 0.f;
#pragma unroll
  for (int s = 0; s < SPLIT; ++s) {
    wk[s] = exp2f(e[s].x - M);
    den += e[s].y * wk[s];
  }
  float inv = 1.f / den;
#pragma unroll
  for (int s = 0; s < SPLIT; ++s) wk[s] *= inv;

  bf16x8 bfr[4];
#pragma unroll
  for (int cc = 0; cc < 4; ++cc) {
    float a8[8];
#pragma unroll
    for (int j = 0; j < 8; ++j) a8[j] = 0.f;
#pragma unroll
    for (int s = 0; s < SPLIT; ++s) {
      bf16x8 a = ld_frag(Op + ((size_t)(s * 4 + b) * NSP + nl) * 128 + cc * 32 + g * 8);
#pragma unroll
      for (int j = 0; j < 8; ++j) a8[j] += (float)a[j] * wk[s];
    }
#pragma unroll
    for (int j = 0; j < 8; ++j) bfr[cc][j] = (__bf16)a8[j];
  }

  f32x4 acc[8];
#pragma unroll
  for (int oc = 0; oc < 8; ++oc)
#pragma unroll
    for (int rr = 0; rr < 4; ++rr) acc[oc][rr] = bo[oc * 16 + g * 4 + rr];
#pragma unroll
  for (int oc = 0; oc < 8; ++oc) {
#pragma unroll
    for (int cc = 0; cc < 4; ++cc) {
      bf16x8 a = ld_frag(wob + (oc * 16 + r) * 128 + cc * 32 + g * 8);
      acc[oc] = MFMA16(a, bfr[cc], acc[oc]);
    }
  }
#pragma unroll
  for (int oc = 0; oc < 8; ++oc) {
#pragma unroll
    for (int rr = 0; rr < 4; ++rr) {
      int o = oc * 16 + g * 4 + rr;
      size_t idx = ((size_t)(b * 128 + o) << 12) + nl;
      out[idx] = acc[oc][rr] + xq[idx];
    }
  }
}

extern "C" void kernel_launch(void* const* d_in, const int* in_sizes, int n_in,
                              void* d_out, int out_size, void* d_ws, size_t ws_size,
                              hipStream_t stream) {
  const float* xq = (const float*)d_in[0];
  const float* xkv = (const float*)d_in[1];
  const float* Wq = (const float*)d_in[2];
  const float* bq = (const float*)d_in[3];
  const float* Wk = (const float*)d_in[4];
  const float* bk = (const float*)d_in[5];
  const float* Wv = (const float*)d_in[6];
  const float* bv = (const float*)d_in[7];
  const float* Wo = (const float*)d_in[8];
  const float* bo = (const float*)d_in[9];
  float* out = (float*)d_out;

  char* ws = (char*)d_ws;
  __bf16* wqb = (__bf16*)(ws);
  __bf16* wkb = (__bf16*)(ws + 32768);
  __bf16* wvb = (__bf16*)(ws + 98304);
  __bf16* wob = (__bf16*)(ws + 163840);
  float* bqs = (float*)(ws + 196608);
  __bf16* Qt = (__bf16*)(ws + 197120);
  __bf16* Kt = (__bf16*)(ws + 197120 + 4194304);
  __bf16* Vm = (__bf16*)(ws + 197120 + 2 * 4194304);
  __bf16* Op = (__bf16*)(ws + 197120 + 3 * 4194304);
  float2* Ml = (float2*)(ws + 197120 + 3 * 4194304 + 16777216);

  k_prep<<<dim3(384), dim3(256), 0, stream>>>(Wq, bq, Wk, Wv, Wo, wqb, wkb, wvb, wob, bqs);
  k_proj<<<dim3(512), dim3(256), 0, stream>>>(xq, xkv, wqb, wkb, wvb, bqs, bk, bv,
                                              Qt, Kt, Vm);

  const size_t need4 = 197120ull + 3ull * 4194304 + 16777216 + 524288;
  if (ws_size >= need4) {
    k_flash<4><<<dim3(512), dim3(256), 0, stream>>>(Qt, Kt, Vm, Op, Ml);
    k_oproj<4><<<dim3(256), dim3(256), 0, stream>>>(Op, Ml, wob, bo, xq, out);
  } else {
    k_flash<2><<<dim3(256), dim3(256), 0, stream>>>(Qt, Kt, Vm, Op, Ml);
    k_oproj<2><<<dim3(256), dim3(256), 0, stream>>>(Op, Ml, wob, bo, xq, out);
  }
}